// Round 9
// baseline (61.588 us; speedup 1.0000x reference)
//
#include <hip/hip_runtime.h>
#include <hip/hip_bf16.h>
#include <stdint.h>

// ---------------------------------------------------------------------------
// out[b,t,a,:] = (state_in[b,t,a,:] @ readin[session[b]]) @ project
// SINGLE fused kernel, grid 2048 = b(128) x mt(8) x nt(2), 256 thr.
// Prologue: W[i][o] = sum_h R[i][h] P[h][o] via mfma(R_frag(direct global),
//   P_frag(LDS transposed)), stored bf16 to Bs[kslot=i>>3][row=o] via
//   ds_write_b64. Main: A (X f32) wave-private gl_lds double-buffer, counted
//   vmcnt(4), ZERO main-loop barriers; mfma(W,X) -> D[o][m] -> dwordx4 stores.
// LDS 80KB: Bs 48KB @0 (Pl 16KB overlays pre-store) | A 4w x 2 x 4KB @48K.
// ---------------------------------------------------------------------------

typedef short    bf16x8 __attribute__((ext_vector_type(8)));
typedef float    f32x4  __attribute__((ext_vector_type(4)));
typedef uint32_t u32x2  __attribute__((ext_vector_type(2)));
typedef uint32_t u32x4  __attribute__((ext_vector_type(4)));

#define NB    128
#define MPB   1024
#define INF   192
#define RDIM  64
#define OUTF  256

#define WAIT_VM4()   asm volatile("s_waitcnt vmcnt(4)" ::: "memory")
#define WAIT_VM0()   asm volatile("s_waitcnt vmcnt(0)" ::: "memory")
#define WAIT_LGKM0() asm volatile("s_waitcnt lgkmcnt(0)" ::: "memory")

__device__ __forceinline__ uint16_t f2bf(float f) {
    union { float f; uint32_t u; } v; v.f = f;
    return (uint16_t)((v.u + 0x7fffu + ((v.u >> 16) & 1u)) >> 16);
}
__device__ __forceinline__ uint32_t pack2(float a, float b) {
    return (uint32_t)f2bf(a) | ((uint32_t)f2bf(b) << 16);
}
__device__ __forceinline__ bf16x8 cvt8(f32x4 a, f32x4 b) {
    union { __hip_bfloat162 h2[4]; bf16x8 h; } r;
    r.h2[0] = __float22bfloat162_rn({a[0], a[1]});
    r.h2[1] = __float22bfloat162_rn({a[2], a[3]});
    r.h2[2] = __float22bfloat162_rn({b[0], b[1]});
    r.h2[3] = __float22bfloat162_rn({b[2], b[3]});
    return r.h;
}
__device__ __forceinline__ void gl_lds16(const void* g, void* l) {
    auto gp = (const __attribute__((address_space(1))) uint32_t*)(uintptr_t)g;
    auto lp = (__attribute__((address_space(3))) uint32_t*)(uintptr_t)l;
    __builtin_amdgcn_global_load_lds(gp, lp, 16, 0, 0);
}

__global__ __launch_bounds__(256, 2) void fused_gemm(
    const float* __restrict__ X,        // [128][1024][192]
    const int*   __restrict__ session,  // [128]
    const float* __restrict__ readin,   // [512][192][64]
    const float* __restrict__ project,  // [64][256]
    float*       __restrict__ Y)        // [128][1024][256]
{
    __shared__ __attribute__((aligned(16))) uint8_t arena[81920];

    const int bid0 = blockIdx.x;
    const int bid  = ((bid0 & 7) << 8) | (bid0 >> 3);   // bijective XCD swizzle
    const int b  = bid >> 4;
    const int mt = (bid >> 1) & 7;
    const int nt = bid & 1;
    const int t  = threadIdx.x, l = t & 63, w = t >> 6;
    const int lr = l & 15, lk = l >> 4;

    const float* Xb = X + ((size_t)b * MPB + mt * 128) * INF;
    float*       Yb = Y + ((size_t)b * MPB + mt * 128) * OUTF + nt * 128;

    // ---- A staging (wave-private, [row 0..31][kq^row&7] 16B units) --------
    uint8_t* Ab = arena + 49152 + w * 8192;
    const float* Aw = Xb + (size_t)(w * 32) * INF;
    int asrc[4];
#pragma unroll
    for (int c = 0; c < 4; ++c) {
        int i   = c * 64 + l;
        int row = i >> 3;
        int kq  = (i & 7) ^ (row & 7);
        asrc[c] = row * INF + kq * 4;
    }
    auto stage = [&](int kk, int buf) {
#pragma unroll
        for (int c = 0; c < 4; ++c)
            gl_lds16(Aw + asrc[c] + kk * 32, Ab + buf * 4096 + c * 1024);
    };

    // issue first two A stages immediately: latency hides under the prologue
    stage(0, 0);
    stage(1, 1);

    // ================= prologue ============================================
    {
        uint16_t* Pl = (uint16_t*)arena;             // [128 o][64 h] swz, 16KB
        const float* Rg = readin + (size_t)session[b] * (INF * RDIM);

        // stage P^T slice (o = nt*128 .. +128), XOR-swizzled h-groups
        {
            int h  = t >> 2;
            int og = (t & 3) * 32;
            const float* Pg = project + (size_t)h * OUTF + nt * 128 + og;
#pragma unroll
            for (int q = 0; q < 8; ++q) {
                f32x4 v = *(const f32x4*)(Pg + q * 4);
#pragma unroll
                for (int e = 0; e < 4; ++e) {
                    int o = og + q * 4 + e;
                    Pl[o * 64 + (((h >> 3) ^ (o & 7)) << 3) + (h & 7)] = f2bf(v[e]);
                }
            }
        }
        __syncthreads();   // Pl ready

        // W[i][o]: wave w covers i-blocks ib = w*3 .. w*3+2 (48 rows), all o.
        f32x4 wacc[3][8];
#pragma unroll
        for (int ii = 0; ii < 3; ++ii)
#pragma unroll
            for (int ob = 0; ob < 8; ++ob) wacc[ii][ob] = f32x4{0.f,0.f,0.f,0.f};

#pragma unroll
        for (int kk = 0; kk < 2; ++kk) {
            bf16x8 rf[3];
#pragma unroll
            for (int ii = 0; ii < 3; ++ii) {
                const float* p = Rg + (size_t)((w * 3 + ii) * 16 + lr) * RDIM
                               + kk * 32 + lk * 8;
                rf[ii] = cvt8(*(const f32x4*)p, *(const f32x4*)(p + 4));
            }
            const int kg = kk * 4 + lk;
#pragma unroll
            for (int ob = 0; ob < 8; ++ob) {
                int o = ob * 16 + lr;
                bf16x8 pf = *(const bf16x8*)&Pl[o * 64 + ((kg ^ (o & 7)) << 3)];
#pragma unroll
                for (int ii = 0; ii < 3; ++ii)
                    wacc[ii][ob] = __builtin_amdgcn_mfma_f32_16x16x32_bf16(
                        rf[ii], pf, wacc[ii][ob], 0, 0, 0);
            }
        }
        __syncthreads();   // all Pl reads retired; Bs region free to overwrite

        // store W frags: D[i = ib*16 + lk*4 + j][o = ob*16 + lr] -> b64 each
        uint8_t* BsB = arena;
#pragma unroll
        for (int ii = 0; ii < 3; ++ii) {
            int ib = w * 3 + ii;
            int ubase = (ib * 2 + (lk >> 1)) * 128;      // unit row (kslot)
#pragma unroll
            for (int ob = 0; ob < 8; ++ob) {
                u32x2 d;
                d[0] = pack2(wacc[ii][ob][0], wacc[ii][ob][1]);
                d[1] = pack2(wacc[ii][ob][2], wacc[ii][ob][3]);
                *(u32x2*)&BsB[(size_t)(ubase + ob * 16 + lr) * 16 + (lk & 1) * 8] = d;
            }
        }
        __syncthreads();   // Bs ready (drains vmcnt -> stage(0/1) complete)
    }

    // ================= main: zero barriers =================================
    f32x4 acc[2][8];
#pragma unroll
    for (int m = 0; m < 2; ++m)
#pragma unroll
        for (int n = 0; n < 8; ++n) acc[m][n] = f32x4{0.f, 0.f, 0.f, 0.f};

    const int a0s = ((2 * lk)     ^ (lr & 7)) << 4;
    const int a1s = ((2 * lk + 1) ^ (lr & 7)) << 4;

#pragma unroll
    for (int kk = 0; kk < 6; ++kk) {
        if (kk < 5) { WAIT_VM4(); } else { WAIT_VM0(); }
        __builtin_amdgcn_sched_barrier(0);

        const uint8_t* Abuf = Ab + (kk & 1) * 4096;
        bf16x8 af[2], bfr[8];
#pragma unroll
        for (int m = 0; m < 2; ++m) {
            const uint8_t* p = Abuf + (m * 16 + lr) * 128;
            f32x4 lo = *(const f32x4*)(p + a0s);
            f32x4 hi = *(const f32x4*)(p + a1s);
            af[m] = cvt8(lo, hi);
        }
#pragma unroll
        for (int n = 0; n < 8; ++n)
            bfr[n] = *(const bf16x8*)(arena
                        + (((kk * 4 + lk) * 128 + n * 16 + lr) << 4));

        WAIT_LGKM0();                       // buf reads retired before reuse
        __builtin_amdgcn_sched_barrier(0);
        if (kk < 4) stage(kk + 2, kk & 1);

        // mfma(W_frag, X_frag): D[o][m] -> lane owns 4 consecutive o-cols
#pragma unroll
        for (int m = 0; m < 2; ++m)
#pragma unroll
            for (int n = 0; n < 8; ++n)
                acc[m][n] = __builtin_amdgcn_mfma_f32_16x16x32_bf16(
                    bfr[n], af[m], acc[m][n], 0, 0, 0);
    }

    // epilogue: Y[m*16+lr][n*16 + lk*4 + 0..3] = acc[m][n] (dwordx4)
#pragma unroll
    for (int m = 0; m < 2; ++m) {
        float* yr = Yb + (size_t)(w * 32 + m * 16 + lr) * OUTF + lk * 4;
#pragma unroll
        for (int n = 0; n < 8; ++n)
            *(f32x4*)(yr + n * 16) = acc[m][n];
    }
}

extern "C" void kernel_launch(void* const* d_in, const int* in_sizes, int n_in,
                              void* d_out, int out_size, void* d_ws, size_t ws_size,
                              hipStream_t stream) {
    (void)in_sizes; (void)n_in; (void)out_size; (void)d_ws; (void)ws_size;
    const float* state   = (const float*)d_in[0];
    const int*   session = (const int*)  d_in[1];
    const float* readin  = (const float*)d_in[2];
    const float* project = (const float*)d_in[3];
    float*       out     = (float*)d_out;

    hipLaunchKernelGGL(fused_gemm, dim3(2048), dim3(256), 0, stream,
                       state, session, readin, project, out);
}

// Round 10
// 59.309 us; speedup vs baseline: 1.0384x; 1.0384x over previous
//
#include <hip/hip_runtime.h>
#include <hip/hip_bf16.h>
#include <stdint.h>

// ---------------------------------------------------------------------------
// out[b,t,a,:] = (state_in[b,t,a,:] @ readin[session[b]]) @ project
// SINGLE fused kernel (R8 structure + mfma-swap epilogue).
// Per block (b, mt, nt):
//   prologue: W panel (128 o x 192 i) = readin[s]^T @ project slice, computed
//     with MFMA from LDS-staged R,P and stored bf16 into LDS Bs[kslot][row].
//   main: A (X, f32) streamed per-wave-private via global_load_lds (2 bufs,
//     depth-2, counted per-wave vmcnt(4)); ZERO barriers in the main loop.
//     mfma(W_frag, X_frag) -> D[o][m] -> lane owns 4 consecutive o-cols
//     -> epilogue is 16 global_store_dwordx4 instead of 64 scalar stores.
// LDS arena 80KB: Bs 48KB | A 4 waves x 2 x 4KB (prologue overlays R,P).
// ---------------------------------------------------------------------------

typedef short    bf16x8 __attribute__((ext_vector_type(8)));
typedef float    f32x4  __attribute__((ext_vector_type(4)));
typedef uint32_t u32x4  __attribute__((ext_vector_type(4)));

#define NB    128   // batch
#define MPB   1024  // rows per batch = T*A
#define INF   192   // K of main GEMM
#define RDIM  64
#define OUTF  256

#define WAIT_VM4()   asm volatile("s_waitcnt vmcnt(4)" ::: "memory")
#define WAIT_VM0()   asm volatile("s_waitcnt vmcnt(0)" ::: "memory")
#define WAIT_LGKM0() asm volatile("s_waitcnt lgkmcnt(0)" ::: "memory")

// round-to-nearest-even f32 -> bf16 bits
__device__ __forceinline__ uint16_t f2bf(float f) {
    union { float f; uint32_t u; } v; v.f = f;
    return (uint16_t)((v.u + 0x7fffu + ((v.u >> 16) & 1u)) >> 16);
}
__device__ __forceinline__ uint32_t pack2(float a, float b) {
    return (uint32_t)f2bf(a) | ((uint32_t)f2bf(b) << 16);
}
// packed f32x8 -> bf16x8 via v_cvt_pk_bf16_f32
__device__ __forceinline__ bf16x8 cvt8(f32x4 a, f32x4 b) {
    union { __hip_bfloat162 h2[4]; bf16x8 h; } r;
    r.h2[0] = __float22bfloat162_rn({a[0], a[1]});
    r.h2[1] = __float22bfloat162_rn({a[2], a[3]});
    r.h2[2] = __float22bfloat162_rn({b[0], b[1]});
    r.h2[3] = __float22bfloat162_rn({b[2], b[3]});
    return r.h;
}
// global -> LDS direct copy, 16B/lane; LDS dest wave-uniform base.
__device__ __forceinline__ void gl_lds16(const void* g, void* l) {
    auto gp = (const __attribute__((address_space(1))) uint32_t*)(uintptr_t)g;
    auto lp = (__attribute__((address_space(3))) uint32_t*)(uintptr_t)l;
    __builtin_amdgcn_global_load_lds(gp, lp, 16, 0, 0);
}

// ---------------------------------------------------------------------------
// fused: grid 2048 = b(128) x mt(8) x nt(2), XCD-swizzled; block 256 thr.
// ---------------------------------------------------------------------------
__global__ __launch_bounds__(256, 2) void fused_gemm(
    const float* __restrict__ X,        // [128][1024][192]
    const int*   __restrict__ session,  // [128]
    const float* __restrict__ readin,   // [512][192][64]
    const float* __restrict__ project,  // [64][256]
    float*       __restrict__ Y)        // [128][1024][256]
{
    __shared__ __attribute__((aligned(16))) uint8_t arena[81920];

    const int bid0 = blockIdx.x;
    const int bid  = ((bid0 & 7) << 8) | (bid0 >> 3);   // bijective XCD swizzle
    const int b  = bid >> 4;
    const int mt = (bid >> 1) & 7;
    const int nt = bid & 1;
    const int t  = threadIdx.x, l = t & 63, w = t >> 6;
    const int lr = l & 15, lk = l >> 4;

    const float* Xb = X + ((size_t)b * MPB + mt * 128) * INF;
    float*       Yb = Y + ((size_t)b * MPB + mt * 128) * OUTF + nt * 128;

    // ================= prologue: W panel -> Bs (bf16, [kslot][row]) =========
    {
        uint16_t* Rl = (uint16_t*)arena;             // [192][64] swz, 24KB
        uint16_t* Pl = (uint16_t*)(arena + 49152);   // [128][64] swz, 16KB
        const float* Rg = readin + (size_t)session[b] * (INF * RDIM);

        // stage R (192x64 f32 -> bf16, XOR-swizzled) — coalesced 16 f32/thread
#pragma unroll
        for (int c = 0; c < 3; ++c) {
            int idx = c * 4096 + t * 16;
            int row = idx >> 6;
            int kg0 = (idx & 63) >> 3;
            f32x4 v0 = *(const f32x4*)(Rg + idx);
            f32x4 v1 = *(const f32x4*)(Rg + idx + 4);
            f32x4 v2 = *(const f32x4*)(Rg + idx + 8);
            f32x4 v3 = *(const f32x4*)(Rg + idx + 12);
            u32x4 d0, d1;
            d0[0] = pack2(v0[0], v0[1]); d0[1] = pack2(v0[2], v0[3]);
            d0[2] = pack2(v1[0], v1[1]); d0[3] = pack2(v1[2], v1[3]);
            d1[0] = pack2(v2[0], v2[1]); d1[1] = pack2(v2[2], v2[3]);
            d1[2] = pack2(v3[0], v3[1]); d1[3] = pack2(v3[2], v3[3]);
            *(u32x4*)&Rl[row * 64 + (((kg0    ) ^ (row & 7)) << 3)] = d0;
            *(u32x4*)&Rl[row * 64 + (((kg0 + 1) ^ (row & 7)) << 3)] = d1;
        }
        // stage P^T slice (o = nt*128 .. +128)
        {
            int h  = t >> 2;
            int og = (t & 3) * 32;
            const float* Pg = project + (size_t)h * OUTF + nt * 128 + og;
#pragma unroll
            for (int q = 0; q < 8; ++q) {
                f32x4 v = *(const f32x4*)(Pg + q * 4);
#pragma unroll
                for (int e = 0; e < 4; ++e) {
                    int o = og + q * 4 + e;
                    Pl[o * 64 + (((h >> 3) ^ (o & 7)) << 3) + (h & 7)] = f2bf(v[e]);
                }
            }
        }
        __syncthreads();

        const int wm = w >> 1, wn = w & 1;
        f32x4 acc[4][6];
#pragma unroll
        for (int m = 0; m < 4; ++m)
#pragma unroll
            for (int n = 0; n < 6; ++n) acc[m][n] = f32x4{0.f, 0.f, 0.f, 0.f};

#pragma unroll
        for (int kk = 0; kk < 2; ++kk) {
            int kg = kk * 4 + lk;
            bf16x8 a[4], bb[6];
#pragma unroll
            for (int m = 0; m < 4; ++m) {
                int row = wm * 64 + m * 16 + lr;
                a[m] = *(const bf16x8*)&Pl[row * 64 + ((kg ^ (row & 7)) << 3)];
            }
#pragma unroll
            for (int n = 0; n < 6; ++n) {
                int col = wn * 96 + n * 16 + lr;
                bb[n] = *(const bf16x8*)&Rl[col * 64 + ((kg ^ (col & 7)) << 3)];
            }
#pragma unroll
            for (int m = 0; m < 4; ++m)
#pragma unroll
                for (int n = 0; n < 6; ++n)
                    acc[m][n] = __builtin_amdgcn_mfma_f32_16x16x32_bf16(
                        a[m], bb[n], acc[m][n], 0, 0, 0);
        }
        __syncthreads();   // all Rl/Pl reads complete before overwrite

        // store W frags bf16 into Bs[kslot=i>>3][row=o] (overwrites Rl region)
        uint16_t* Bs16 = (uint16_t*)arena;
#pragma unroll
        for (int m = 0; m < 4; ++m) {
            int o0 = wm * 64 + m * 16 + lk * 4;
#pragma unroll
            for (int n = 0; n < 6; ++n) {
                int i = wn * 96 + n * 16 + lr;
#pragma unroll
                for (int j = 0; j < 4; ++j)
                    Bs16[((i >> 3) * 128 + (o0 + j)) * 8 + (i & 7)]
                        = f2bf(acc[m][n][j]);
            }
        }
        __syncthreads();   // W panel ready; Pl/A-region free
    }

    // ================= main: zero barriers ==================================
    // A wave-private: wave w owns rows w*32 .. +32. LDS [row 0..31][kq^row&7]
    // 16B units, 4KB per buf, 2 bufs. Source pre-swizzled (row-contiguous).
    uint8_t* Ab = arena + 49152 + w * 8192;
    const float* Aw = Xb + (size_t)(w * 32) * INF;

    int asrc[4];
#pragma unroll
    for (int c = 0; c < 4; ++c) {
        int i   = c * 64 + l;
        int row = i >> 3;                  // 0..31
        int kq  = (i & 7) ^ (row & 7);     // pre-swizzled source quad
        asrc[c] = row * INF + kq * 4;
    }
    auto stage = [&](int kk, int buf) {
#pragma unroll
        for (int c = 0; c < 4; ++c)
            gl_lds16(Aw + asrc[c] + kk * 32, Ab + buf * 4096 + c * 1024);
    };

    stage(0, 0);
    stage(1, 1);

    f32x4 acc[2][8];
#pragma unroll
    for (int m = 0; m < 2; ++m)
#pragma unroll
        for (int n = 0; n < 8; ++n) acc[m][n] = f32x4{0.f, 0.f, 0.f, 0.f};

    const int a0s = ((2 * lk)     ^ (lr & 7)) << 4;   // read-side swizzle
    const int a1s = ((2 * lk + 1) ^ (lr & 7)) << 4;

#pragma unroll
    for (int kk = 0; kk < 6; ++kk) {
        if (kk < 5) { WAIT_VM4(); } else { WAIT_VM0(); }   // own stage kk done
        __builtin_amdgcn_sched_barrier(0);

        const uint8_t* Abuf = Ab + (kk & 1) * 4096;
        bf16x8 af[2], bfr[8];
#pragma unroll
        for (int m = 0; m < 2; ++m) {
            const uint8_t* p = Abuf + (m * 16 + lr) * 128;
            f32x4 lo = *(const f32x4*)(p + a0s);
            f32x4 hi = *(const f32x4*)(p + a1s);
            af[m] = cvt8(lo, hi);
        }
#pragma unroll
        for (int n = 0; n < 8; ++n)
            bfr[n] = *(const bf16x8*)(arena
                        + (((kk * 4 + lk) * 128 + n * 16 + lr) << 4));

        WAIT_LGKM0();                       // buf reads retired before reuse
        __builtin_amdgcn_sched_barrier(0);
        if (kk < 4) stage(kk + 2, kk & 1);  // fire-and-forget, depth-2

        // mfma(W_frag, X_frag): A/B frag lane layouts are identical, so the
        // swap needs no data movement; D becomes [o][m-row] -> lane owns 4
        // consecutive o columns (verified R9: absmax unchanged).
#pragma unroll
        for (int m = 0; m < 2; ++m)
#pragma unroll
            for (int n = 0; n < 8; ++n)
                acc[m][n] = __builtin_amdgcn_mfma_f32_16x16x32_bf16(
                    bfr[n], af[m], acc[m][n], 0, 0, 0);
    }

    // epilogue: Y[w*32 + m*16 + lr][n*16 + lk*4 + 0..3] = acc[m][n] (dwordx4)
#pragma unroll
    for (int m = 0; m < 2; ++m) {
        float* yr = Yb + (size_t)(w * 32 + m * 16 + lr) * OUTF + lk * 4;
#pragma unroll
        for (int n = 0; n < 8; ++n)
            *(f32x4*)(yr + n * 16) = acc[m][n];
    }
}

extern "C" void kernel_launch(void* const* d_in, const int* in_sizes, int n_in,
                              void* d_out, int out_size, void* d_ws, size_t ws_size,
                              hipStream_t stream) {
    (void)in_sizes; (void)n_in; (void)out_size; (void)d_ws; (void)ws_size;
    const float* state   = (const float*)d_in[0];
    const int*   session = (const int*)  d_in[1];
    const float* readin  = (const float*)d_in[2];
    const float* project = (const float*)d_in[3];
    float*       out     = (float*)d_out;

    hipLaunchKernelGGL(fused_gemm, dim3(2048), dim3(256), 0, stream,
                       state, session, readin, project, out);
}

// Round 11
// 58.527 us; speedup vs baseline: 1.0523x; 1.0133x over previous
//
#include <hip/hip_runtime.h>
#include <hip/hip_bf16.h>
#include <stdint.h>

// ---------------------------------------------------------------------------
// out[b,t,a,:] = (state_in[b,t,a,:] @ readin[session[b]]) @ project
// SINGLE fused kernel. R8 structure, but A never touches LDS:
//   prologue: W panel (128 o x 192 i) via MFMA from LDS-staged R,P; stored
//     bf16 into Bs[kslot][row] (arena reused: Rl@0, Pl@24K -> Bs 48KB).
//   main: A (X f32) loaded straight to registers with inline-asm
//     global_load_dwordx4 (compiler cannot sink it), double-buffered,
//     per-wave counted vmcnt(4), ZERO barriers, zero A LDS traffic.
// LDS = 48KB -> 3 blocks/CU (12 waves/CU, 1.5x R8's TLP).
// ---------------------------------------------------------------------------

typedef short    bf16x8 __attribute__((ext_vector_type(8)));
typedef float    f32x4  __attribute__((ext_vector_type(4)));
typedef uint32_t u32x4  __attribute__((ext_vector_type(4)));

#define NB    128
#define MPB   1024
#define INF   192
#define RDIM  64
#define OUTF  256

#define WAIT_VM4()   asm volatile("s_waitcnt vmcnt(4)" ::: "memory")
#define WAIT_VM0()   asm volatile("s_waitcnt vmcnt(0)" ::: "memory")

__device__ __forceinline__ uint16_t f2bf(float f) {
    union { float f; uint32_t u; } v; v.f = f;
    return (uint16_t)((v.u + 0x7fffu + ((v.u >> 16) & 1u)) >> 16);
}
__device__ __forceinline__ uint32_t pack2(float a, float b) {
    return (uint32_t)f2bf(a) | ((uint32_t)f2bf(b) << 16);
}
__device__ __forceinline__ bf16x8 cvt8(f32x4 a, f32x4 b) {
    union { __hip_bfloat162 h2[4]; bf16x8 h; } r;
    r.h2[0] = __float22bfloat162_rn({a[0], a[1]});
    r.h2[1] = __float22bfloat162_rn({a[2], a[3]});
    r.h2[2] = __float22bfloat162_rn({b[0], b[1]});
    r.h2[3] = __float22bfloat162_rn({b[2], b[3]});
    return r.h;
}
// opaque global load: scheduler can't sink it; we count vmcnt ourselves
__device__ __forceinline__ void gload4(f32x4& d, const float* p) {
    asm volatile("global_load_dwordx4 %0, %1, off"
                 : "=&v"(d) : "v"(p));
}

__global__ __launch_bounds__(256, 3) void fused_gemm(
    const float* __restrict__ X,        // [128][1024][192]
    const int*   __restrict__ session,  // [128]
    const float* __restrict__ readin,   // [512][192][64]
    const float* __restrict__ project,  // [64][256]
    float*       __restrict__ Y)        // [128][1024][256]
{
    __shared__ __attribute__((aligned(16))) uint8_t arena[49152];   // 48 KB

    const int bid0 = blockIdx.x;
    const int bid  = ((bid0 & 7) << 8) | (bid0 >> 3);   // bijective XCD swizzle
    const int b  = bid >> 4;
    const int mt = (bid >> 1) & 7;
    const int nt = bid & 1;
    const int t  = threadIdx.x, l = t & 63, w = t >> 6;
    const int lr = l & 15, lk = l >> 4;

    const float* Xb = X + ((size_t)b * MPB + mt * 128) * INF;
    float*       Yb = Y + ((size_t)b * MPB + mt * 128) * OUTF + nt * 128;

    // ================= prologue: W panel -> Bs (bf16, [kslot][row]) =========
    {
        uint16_t* Rl = (uint16_t*)arena;             // [192][64] swz, 24KB
        uint16_t* Pl = (uint16_t*)(arena + 24576);   // [128][64] swz, 16KB
        const float* Rg = readin + (size_t)session[b] * (INF * RDIM);

        // stage R (192x64 f32 -> bf16, XOR-swizzled) — coalesced 16 f32/thread
#pragma unroll
        for (int c = 0; c < 3; ++c) {
            int idx = c * 4096 + t * 16;
            int row = idx >> 6;
            int kg0 = (idx & 63) >> 3;
            f32x4 v0 = *(const f32x4*)(Rg + idx);
            f32x4 v1 = *(const f32x4*)(Rg + idx + 4);
            f32x4 v2 = *(const f32x4*)(Rg + idx + 8);
            f32x4 v3 = *(const f32x4*)(Rg + idx + 12);
            u32x4 d0, d1;
            d0[0] = pack2(v0[0], v0[1]); d0[1] = pack2(v0[2], v0[3]);
            d0[2] = pack2(v1[0], v1[1]); d0[3] = pack2(v1[2], v1[3]);
            d1[0] = pack2(v2[0], v2[1]); d1[1] = pack2(v2[2], v2[3]);
            d1[2] = pack2(v3[0], v3[1]); d1[3] = pack2(v3[2], v3[3]);
            *(u32x4*)&Rl[row * 64 + (((kg0    ) ^ (row & 7)) << 3)] = d0;
            *(u32x4*)&Rl[row * 64 + (((kg0 + 1) ^ (row & 7)) << 3)] = d1;
        }
        // stage P^T slice (o = nt*128 .. +128)
        {
            int h  = t >> 2;
            int og = (t & 3) * 32;
            const float* Pg = project + (size_t)h * OUTF + nt * 128 + og;
#pragma unroll
            for (int q = 0; q < 8; ++q) {
                f32x4 v = *(const f32x4*)(Pg + q * 4);
#pragma unroll
                for (int e = 0; e < 4; ++e) {
                    int o = og + q * 4 + e;
                    Pl[o * 64 + (((h >> 3) ^ (o & 7)) << 3) + (h & 7)] = f2bf(v[e]);
                }
            }
        }
        __syncthreads();

        const int wm = w >> 1, wn = w & 1;
        f32x4 acc[4][6];
#pragma unroll
        for (int m = 0; m < 4; ++m)
#pragma unroll
            for (int n = 0; n < 6; ++n) acc[m][n] = f32x4{0.f, 0.f, 0.f, 0.f};

#pragma unroll
        for (int kk = 0; kk < 2; ++kk) {
            int kg = kk * 4 + lk;
            bf16x8 a[4], bb[6];
#pragma unroll
            for (int m = 0; m < 4; ++m) {
                int row = wm * 64 + m * 16 + lr;
                a[m] = *(const bf16x8*)&Pl[row * 64 + ((kg ^ (row & 7)) << 3)];
            }
#pragma unroll
            for (int n = 0; n < 6; ++n) {
                int col = wn * 96 + n * 16 + lr;
                bb[n] = *(const bf16x8*)&Rl[col * 64 + ((kg ^ (col & 7)) << 3)];
            }
#pragma unroll
            for (int m = 0; m < 4; ++m)
#pragma unroll
                for (int n = 0; n < 6; ++n)
                    acc[m][n] = __builtin_amdgcn_mfma_f32_16x16x32_bf16(
                        a[m], bb[n], acc[m][n], 0, 0, 0);
        }
        __syncthreads();   // all Rl/Pl reads complete before overwrite

        // store W frags bf16 into Bs[kslot=i>>3][row=o] (overwrites Rl/Pl)
        uint16_t* Bs16 = (uint16_t*)arena;
#pragma unroll
        for (int m = 0; m < 4; ++m) {
            int o0 = wm * 64 + m * 16 + lk * 4;
#pragma unroll
            for (int n = 0; n < 6; ++n) {
                int i = wn * 96 + n * 16 + lr;
#pragma unroll
                for (int j = 0; j < 4; ++j)
                    Bs16[((i >> 3) * 128 + (o0 + j)) * 8 + (i & 7)]
                        = f2bf(acc[m][n][j]);
            }
        }
        __syncthreads();   // Bs ready
    }

    // ================= main: zero barriers, A direct-to-reg =================
    // Lane covers A rows (w*32 + m*16 + lr), k = kk*32 + lk*8 (2 x f32x4/m).
    // Per step: 4 asm loads; depth-2 (8 outstanding), counted vmcnt(4).
    const float* Aw = Xb + (size_t)(w * 32 + lr) * INF + lk * 8;

    f32x4 pa0[4], pa1[4];
    auto issueA = [&](int kk, f32x4* pa) {
        const float* p = Aw + kk * 32;
        gload4(pa[0], p);
        gload4(pa[1], p + 4);
        gload4(pa[2], p + 16 * INF);
        gload4(pa[3], p + 16 * INF + 4);
    };

    issueA(0, pa0);
    issueA(1, pa1);

    f32x4 acc[2][8];
#pragma unroll
    for (int m = 0; m < 2; ++m)
#pragma unroll
        for (int n = 0; n < 8; ++n) acc[m][n] = f32x4{0.f, 0.f, 0.f, 0.f};

#pragma unroll
    for (int kk = 0; kk < 6; ++kk) {
        // B fragment reads (independent of A; Bs is static after prologue)
        bf16x8 bfr[8];
#pragma unroll
        for (int n = 0; n < 8; ++n)
            bfr[n] = *(const bf16x8*)(arena
                        + (((kk * 4 + lk) * 128 + n * 16 + lr) << 4));

        if (kk < 5) { WAIT_VM4(); } else { WAIT_VM0(); }   // A(kk) resident
        __builtin_amdgcn_sched_barrier(0);                  // rule #18 fence

        f32x4* cur = (kk & 1) ? pa1 : pa0;
        bf16x8 af[2];
        af[0] = cvt8(cur[0], cur[1]);
        af[1] = cvt8(cur[2], cur[3]);

        if (kk < 4) issueA(kk + 2, cur);   // reuse regs (WAR via reg deps)

#pragma unroll
        for (int m = 0; m < 2; ++m)
#pragma unroll
            for (int n = 0; n < 8; ++n)
                acc[m][n] = __builtin_amdgcn_mfma_f32_16x16x32_bf16(
                    af[m], bfr[n], acc[m][n], 0, 0, 0);
    }

    // epilogue (R8-exact): D row=(lane>>4)*4+j, col=lane&15
#pragma unroll
    for (int m = 0; m < 2; ++m) {
        int r0 = w * 32 + m * 16 + lk * 4;
#pragma unroll
        for (int n = 0; n < 8; ++n) {
            int c0 = n * 16 + lr;
#pragma unroll
            for (int j = 0; j < 4; ++j)
                Yb[(size_t)(r0 + j) * OUTF + c0] = acc[m][n][j];
        }
    }
}

extern "C" void kernel_launch(void* const* d_in, const int* in_sizes, int n_in,
                              void* d_out, int out_size, void* d_ws, size_t ws_size,
                              hipStream_t stream) {
    (void)in_sizes; (void)n_in; (void)out_size; (void)d_ws; (void)ws_size;
    const float* state   = (const float*)d_in[0];
    const int*   session = (const int*)  d_in[1];
    const float* readin  = (const float*)d_in[2];
    const float* project = (const float*)d_in[3];
    float*       out     = (float*)d_out;

    hipLaunchKernelGGL(fused_gemm, dim3(2048), dim3(256), 0, stream,
                       state, session, readin, project, out);
}

// Round 12
// 45.462 us; speedup vs baseline: 1.3547x; 1.2874x over previous
//
#include <hip/hip_runtime.h>
#include <hip/hip_bf16.h>
#include <stdint.h>

// ---------------------------------------------------------------------------
// out[b,t,a,:] = (state_in[b,t,a,:] @ readin[session[b]]) @ project
// SINGLE fused kernel. R8 structure with M-tile 256 (prologue amortized 2x).
// grid 1024 = b(128) x mt(4) x nt(2); block 256 thr (4 waves).
//   prologue (R8-verbatim): W panel (128 o x 192 i) via MFMA from LDS-staged
//     R,P; stored bf16 into Bs[kslot][row] (48KB @ arena 0).
//   main: flat 12 steps = 2 M-halves x 6 K-steps, full unroll. A staged via
//     global_load_lds (2 wave-private 4KB bufs, depth-2, counted vmcnt(4)),
//     ZERO barriers. Both halves' accumulators stay live (no stores inside
//     the counted-vmcnt window); one epilogue at the end.
// LDS 80KB: Bs 48KB | A 4 waves x 2 x 4KB @48K (prologue overlays Pl there).
// ---------------------------------------------------------------------------

typedef short    bf16x8 __attribute__((ext_vector_type(8)));
typedef float    f32x4  __attribute__((ext_vector_type(4)));
typedef uint32_t u32x4  __attribute__((ext_vector_type(4)));

#define NB    128
#define MPB   1024
#define INF   192
#define RDIM  64
#define OUTF  256

#define WAIT_VM4()   asm volatile("s_waitcnt vmcnt(4)" ::: "memory")
#define WAIT_VM0()   asm volatile("s_waitcnt vmcnt(0)" ::: "memory")
#define WAIT_LGKM0() asm volatile("s_waitcnt lgkmcnt(0)" ::: "memory")

__device__ __forceinline__ uint16_t f2bf(float f) {
    union { float f; uint32_t u; } v; v.f = f;
    return (uint16_t)((v.u + 0x7fffu + ((v.u >> 16) & 1u)) >> 16);
}
__device__ __forceinline__ uint32_t pack2(float a, float b) {
    return (uint32_t)f2bf(a) | ((uint32_t)f2bf(b) << 16);
}
__device__ __forceinline__ bf16x8 cvt8(f32x4 a, f32x4 b) {
    union { __hip_bfloat162 h2[4]; bf16x8 h; } r;
    r.h2[0] = __float22bfloat162_rn({a[0], a[1]});
    r.h2[1] = __float22bfloat162_rn({a[2], a[3]});
    r.h2[2] = __float22bfloat162_rn({b[0], b[1]});
    r.h2[3] = __float22bfloat162_rn({b[2], b[3]});
    return r.h;
}
__device__ __forceinline__ void gl_lds16(const void* g, void* l) {
    auto gp = (const __attribute__((address_space(1))) uint32_t*)(uintptr_t)g;
    auto lp = (__attribute__((address_space(3))) uint32_t*)(uintptr_t)l;
    __builtin_amdgcn_global_load_lds(gp, lp, 16, 0, 0);
}

__global__ __launch_bounds__(256, 2) void fused_gemm(
    const float* __restrict__ X,        // [128][1024][192]
    const int*   __restrict__ session,  // [128]
    const float* __restrict__ readin,   // [512][192][64]
    const float* __restrict__ project,  // [64][256]
    float*       __restrict__ Y)        // [128][1024][256]
{
    __shared__ __attribute__((aligned(16))) uint8_t arena[81920];

    const int bid0 = blockIdx.x;
    const int bid  = ((bid0 & 7) << 7) | (bid0 >> 3);   // bijective (1024%8==0)
    const int b  = bid >> 3;
    const int mt = (bid >> 1) & 3;                       // 256-row tiles
    const int nt = bid & 1;
    const int t  = threadIdx.x, l = t & 63, w = t >> 6;
    const int lr = l & 15, lk = l >> 4;

    const float* Xb = X + ((size_t)b * MPB + mt * 256) * INF;
    float*       Yb = Y + ((size_t)b * MPB + mt * 256) * OUTF + nt * 128;

    // ================= prologue: W panel -> Bs (R8-verbatim) ================
    {
        uint16_t* Rl = (uint16_t*)arena;             // [192][64] swz, 24KB
        uint16_t* Pl = (uint16_t*)(arena + 49152);   // [128][64] swz, 16KB
        const float* Rg = readin + (size_t)session[b] * (INF * RDIM);

#pragma unroll
        for (int c = 0; c < 3; ++c) {
            int idx = c * 4096 + t * 16;
            int row = idx >> 6;
            int kg0 = (idx & 63) >> 3;
            f32x4 v0 = *(const f32x4*)(Rg + idx);
            f32x4 v1 = *(const f32x4*)(Rg + idx + 4);
            f32x4 v2 = *(const f32x4*)(Rg + idx + 8);
            f32x4 v3 = *(const f32x4*)(Rg + idx + 12);
            u32x4 d0, d1;
            d0[0] = pack2(v0[0], v0[1]); d0[1] = pack2(v0[2], v0[3]);
            d0[2] = pack2(v1[0], v1[1]); d0[3] = pack2(v1[2], v1[3]);
            d1[0] = pack2(v2[0], v2[1]); d1[1] = pack2(v2[2], v2[3]);
            d1[2] = pack2(v3[0], v3[1]); d1[3] = pack2(v3[2], v3[3]);
            *(u32x4*)&Rl[row * 64 + (((kg0    ) ^ (row & 7)) << 3)] = d0;
            *(u32x4*)&Rl[row * 64 + (((kg0 + 1) ^ (row & 7)) << 3)] = d1;
        }
        {
            int h  = t >> 2;
            int og = (t & 3) * 32;
            const float* Pg = project + (size_t)h * OUTF + nt * 128 + og;
#pragma unroll
            for (int q = 0; q < 8; ++q) {
                f32x4 v = *(const f32x4*)(Pg + q * 4);
#pragma unroll
                for (int e = 0; e < 4; ++e) {
                    int o = og + q * 4 + e;
                    Pl[o * 64 + (((h >> 3) ^ (o & 7)) << 3) + (h & 7)] = f2bf(v[e]);
                }
            }
        }
        __syncthreads();

        const int wm = w >> 1, wn = w & 1;
        f32x4 acc[4][6];
#pragma unroll
        for (int m = 0; m < 4; ++m)
#pragma unroll
            for (int n = 0; n < 6; ++n) acc[m][n] = f32x4{0.f, 0.f, 0.f, 0.f};

#pragma unroll
        for (int kk = 0; kk < 2; ++kk) {
            int kg = kk * 4 + lk;
            bf16x8 a[4], bb[6];
#pragma unroll
            for (int m = 0; m < 4; ++m) {
                int row = wm * 64 + m * 16 + lr;
                a[m] = *(const bf16x8*)&Pl[row * 64 + ((kg ^ (row & 7)) << 3)];
            }
#pragma unroll
            for (int n = 0; n < 6; ++n) {
                int col = wn * 96 + n * 16 + lr;
                bb[n] = *(const bf16x8*)&Rl[col * 64 + ((kg ^ (col & 7)) << 3)];
            }
#pragma unroll
            for (int m = 0; m < 4; ++m)
#pragma unroll
                for (int n = 0; n < 6; ++n)
                    acc[m][n] = __builtin_amdgcn_mfma_f32_16x16x32_bf16(
                        a[m], bb[n], acc[m][n], 0, 0, 0);
        }
        __syncthreads();

        uint16_t* Bs16 = (uint16_t*)arena;
#pragma unroll
        for (int m = 0; m < 4; ++m) {
            int o0 = wm * 64 + m * 16 + lk * 4;
#pragma unroll
            for (int n = 0; n < 6; ++n) {
                int i = wn * 96 + n * 16 + lr;
#pragma unroll
                for (int j = 0; j < 4; ++j)
                    Bs16[((i >> 3) * 128 + (o0 + j)) * 8 + (i & 7)]
                        = f2bf(acc[m][n][j]);
            }
        }
        __syncthreads();   // Bs ready
    }

    // ================= main: 12 flat steps, zero barriers ===================
    uint8_t* Ab = arena + 49152 + w * 8192;
    int asrc[4];
#pragma unroll
    for (int c = 0; c < 4; ++c) {
        int i   = c * 64 + l;
        int row = i >> 3;
        int kq  = (i & 7) ^ (row & 7);
        asrc[c] = row * INF + kq * 4;
    }
    const float* Aw = Xb + (size_t)(w * 32) * INF;   // half 0 base

    auto stage = [&](int s, int buf) {               // s compile-time (unroll)
        const float* src = Aw + (s / 6) * (128 * INF) + (s % 6) * 32;
#pragma unroll
        for (int c = 0; c < 4; ++c)
            gl_lds16(src + asrc[c], Ab + buf * 4096 + c * 1024);
    };

    stage(0, 0);
    stage(1, 1);

    f32x4 accA[2][8], accB[2][8];
#pragma unroll
    for (int m = 0; m < 2; ++m)
#pragma unroll
        for (int n = 0; n < 8; ++n) {
            accA[m][n] = f32x4{0.f, 0.f, 0.f, 0.f};
            accB[m][n] = f32x4{0.f, 0.f, 0.f, 0.f};
        }

    const int a0s = ((2 * lk)     ^ (lr & 7)) << 4;
    const int a1s = ((2 * lk + 1) ^ (lr & 7)) << 4;

#pragma unroll
    for (int s = 0; s < 12; ++s) {
        if (s < 10) { WAIT_VM4(); } else { WAIT_VM0(); }
        __builtin_amdgcn_sched_barrier(0);

        const uint8_t* Abuf = Ab + (s & 1) * 4096;
        const int kk = s % 6;
        bf16x8 af[2], bfr[8];
#pragma unroll
        for (int m = 0; m < 2; ++m) {
            const uint8_t* p = Abuf + (m * 16 + lr) * 128;
            f32x4 lo = *(const f32x4*)(p + a0s);
            f32x4 hi = *(const f32x4*)(p + a1s);
            af[m] = cvt8(lo, hi);
        }
#pragma unroll
        for (int n = 0; n < 8; ++n)
            bfr[n] = *(const bf16x8*)(arena
                        + (((kk * 4 + lk) * 128 + n * 16 + lr) << 4));

        WAIT_LGKM0();                       // buf reads retired before reuse
        __builtin_amdgcn_sched_barrier(0);
        if (s < 10) stage(s + 2, s & 1);    // fire-and-forget, depth-2

        if (s < 6) {
#pragma unroll
            for (int m = 0; m < 2; ++m)
#pragma unroll
                for (int n = 0; n < 8; ++n)
                    accA[m][n] = __builtin_amdgcn_mfma_f32_16x16x32_bf16(
                        af[m], bfr[n], accA[m][n], 0, 0, 0);
        } else {
#pragma unroll
            for (int m = 0; m < 2; ++m)
#pragma unroll
                for (int n = 0; n < 8; ++n)
                    accB[m][n] = __builtin_amdgcn_mfma_f32_16x16x32_bf16(
                        af[m], bfr[n], accB[m][n], 0, 0, 0);
        }
    }

    // epilogue (R8-exact form), both halves
#pragma unroll
    for (int m = 0; m < 2; ++m) {
        int r0 = w * 32 + m * 16 + lk * 4;
#pragma unroll
        for (int n = 0; n < 8; ++n) {
            int c0 = n * 16 + lr;
#pragma unroll
            for (int j = 0; j < 4; ++j) {
                Yb[(size_t)(r0 + j) * OUTF + c0]       = accA[m][n][j];
                Yb[(size_t)(128 + r0 + j) * OUTF + c0] = accB[m][n][j];
            }
        }
    }
}

extern "C" void kernel_launch(void* const* d_in, const int* in_sizes, int n_in,
                              void* d_out, int out_size, void* d_ws, size_t ws_size,
                              hipStream_t stream) {
    (void)in_sizes; (void)n_in; (void)out_size; (void)d_ws; (void)ws_size;
    const float* state   = (const float*)d_in[0];
    const int*   session = (const int*)  d_in[1];
    const float* readin  = (const float*)d_in[2];
    const float* project = (const float*)d_in[3];
    float*       out     = (float*)d_out;

    hipLaunchKernelGGL(fused_gemm, dim3(1024), dim3(256), 0, stream,
                       state, session, readin, project, out);
}

// Round 13
// 45.329 us; speedup vs baseline: 1.3587x; 1.0029x over previous
//
#include <hip/hip_runtime.h>
#include <hip/hip_bf16.h>
#include <stdint.h>

// ---------------------------------------------------------------------------
// out[b,t,a,:] = (state_in[b,t,a,:] @ readin[session[b]]) @ project
// SINGLE fused kernel. R12 structure (M-tile 256, 12-step barrier-free main
// loop) with a cheaper prologue:
//   - W computed as D[i][o] = mfma(R_frag, P_frag)  (operand swap, R9-proven)
//     -> W store collapses to 24 ds_write_b64 per thread (was 96 scalar b16).
//   - Arena: Rl@0 (24K), Pl@24K (16K), both inside Bs region (48K); A bufs
//     @49152 are prologue-free -> A stage(0)/stage(1) issue at kernel START
//     and their latency hides under the prologue (final barrier drains vmcnt).
// grid 1024 = b(128) x mt(4) x nt(2); block 256 thr; LDS 80KB, 2 blocks/CU.
// ---------------------------------------------------------------------------

typedef short    bf16x8 __attribute__((ext_vector_type(8)));
typedef float    f32x4  __attribute__((ext_vector_type(4)));
typedef uint32_t u32x2  __attribute__((ext_vector_type(2)));
typedef uint32_t u32x4  __attribute__((ext_vector_type(4)));

#define NB    128
#define MPB   1024
#define INF   192
#define RDIM  64
#define OUTF  256

#define WAIT_VM4()   asm volatile("s_waitcnt vmcnt(4)" ::: "memory")
#define WAIT_VM0()   asm volatile("s_waitcnt vmcnt(0)" ::: "memory")
#define WAIT_LGKM0() asm volatile("s_waitcnt lgkmcnt(0)" ::: "memory")

__device__ __forceinline__ uint16_t f2bf(float f) {
    union { float f; uint32_t u; } v; v.f = f;
    return (uint16_t)((v.u + 0x7fffu + ((v.u >> 16) & 1u)) >> 16);
}
__device__ __forceinline__ uint32_t pack2(float a, float b) {
    return (uint32_t)f2bf(a) | ((uint32_t)f2bf(b) << 16);
}
__device__ __forceinline__ bf16x8 cvt8(f32x4 a, f32x4 b) {
    union { __hip_bfloat162 h2[4]; bf16x8 h; } r;
    r.h2[0] = __float22bfloat162_rn({a[0], a[1]});
    r.h2[1] = __float22bfloat162_rn({a[2], a[3]});
    r.h2[2] = __float22bfloat162_rn({b[0], b[1]});
    r.h2[3] = __float22bfloat162_rn({b[2], b[3]});
    return r.h;
}
__device__ __forceinline__ void gl_lds16(const void* g, void* l) {
    auto gp = (const __attribute__((address_space(1))) uint32_t*)(uintptr_t)g;
    auto lp = (__attribute__((address_space(3))) uint32_t*)(uintptr_t)l;
    __builtin_amdgcn_global_load_lds(gp, lp, 16, 0, 0);
}

__global__ __launch_bounds__(256, 2) void fused_gemm(
    const float* __restrict__ X,        // [128][1024][192]
    const int*   __restrict__ session,  // [128]
    const float* __restrict__ readin,   // [512][192][64]
    const float* __restrict__ project,  // [64][256]
    float*       __restrict__ Y)        // [128][1024][256]
{
    __shared__ __attribute__((aligned(16))) uint8_t arena[81920];

    const int bid0 = blockIdx.x;
    const int bid  = ((bid0 & 7) << 7) | (bid0 >> 3);   // bijective (1024%8==0)
    const int b  = bid >> 3;
    const int mt = (bid >> 1) & 3;                       // 256-row tiles
    const int nt = bid & 1;
    const int t  = threadIdx.x, l = t & 63, w = t >> 6;
    const int lr = l & 15, lk = l >> 4;

    const float* Xb = X + ((size_t)b * MPB + mt * 256) * INF;
    float*       Yb = Y + ((size_t)b * MPB + mt * 256) * OUTF + nt * 128;

    // ---- A staging geometry (wave-private bufs @49152, prologue-free) ------
    uint8_t* Ab = arena + 49152 + w * 8192;
    int asrc[4];
#pragma unroll
    for (int c = 0; c < 4; ++c) {
        int i   = c * 64 + l;
        int row = i >> 3;
        int kq  = (i & 7) ^ (row & 7);
        asrc[c] = row * INF + kq * 4;
    }
    const float* Aw = Xb + (size_t)(w * 32) * INF;   // half 0 base

    auto stage = [&](int s, int buf) {               // s compile-time (unroll)
        const float* src = Aw + (s / 6) * (128 * INF) + (s % 6) * 32;
#pragma unroll
        for (int c = 0; c < 4; ++c)
            gl_lds16(src + asrc[c], Ab + buf * 4096 + c * 1024);
    };

    // issue first two A stages NOW: latency hides under the whole prologue;
    // the prologue's final __syncthreads drains vmcnt -> both resident after.
    stage(0, 0);
    stage(1, 1);

    // ================= prologue: W panel -> Bs (bf16, [kslot][row]) =========
    {
        uint16_t* Rl = (uint16_t*)arena;             // [192][64] swz, 24KB @0
        uint16_t* Pl = (uint16_t*)(arena + 24576);   // [128][64] swz, 16KB
        const float* Rg = readin + (size_t)session[b] * (INF * RDIM);

        // stage R (192x64 f32 -> bf16, XOR-swizzled) — coalesced 16 f32/thread
#pragma unroll
        for (int c = 0; c < 3; ++c) {
            int idx = c * 4096 + t * 16;
            int row = idx >> 6;
            int kg0 = (idx & 63) >> 3;
            f32x4 v0 = *(const f32x4*)(Rg + idx);
            f32x4 v1 = *(const f32x4*)(Rg + idx + 4);
            f32x4 v2 = *(const f32x4*)(Rg + idx + 8);
            f32x4 v3 = *(const f32x4*)(Rg + idx + 12);
            u32x4 d0, d1;
            d0[0] = pack2(v0[0], v0[1]); d0[1] = pack2(v0[2], v0[3]);
            d0[2] = pack2(v1[0], v1[1]); d0[3] = pack2(v1[2], v1[3]);
            d1[0] = pack2(v2[0], v2[1]); d1[1] = pack2(v2[2], v2[3]);
            d1[2] = pack2(v3[0], v3[1]); d1[3] = pack2(v3[2], v3[3]);
            *(u32x4*)&Rl[row * 64 + (((kg0    ) ^ (row & 7)) << 3)] = d0;
            *(u32x4*)&Rl[row * 64 + (((kg0 + 1) ^ (row & 7)) << 3)] = d1;
        }
        // stage P^T slice (o = nt*128 .. +128)
        {
            int h  = t >> 2;
            int og = (t & 3) * 32;
            const float* Pg = project + (size_t)h * OUTF + nt * 128 + og;
#pragma unroll
            for (int q = 0; q < 8; ++q) {
                f32x4 v = *(const f32x4*)(Pg + q * 4);
#pragma unroll
                for (int e = 0; e < 4; ++e) {
                    int o = og + q * 4 + e;
                    Pl[o * 64 + (((h >> 3) ^ (o & 7)) << 3) + (h & 7)] = f2bf(v[e]);
                }
            }
        }
        __syncthreads();   // Rl/Pl ready (also drains A stage(0/1) vm ops)

        const int wm = w >> 1, wn = w & 1;
        // D[i][o]: wacc[n][m], i-blocks n=0..5 (wn*96+n*16), o-blocks m=0..3
        f32x4 wacc[6][4];
#pragma unroll
        for (int n = 0; n < 6; ++n)
#pragma unroll
            for (int m = 0; m < 4; ++m) wacc[n][m] = f32x4{0.f, 0.f, 0.f, 0.f};

#pragma unroll
        for (int kk = 0; kk < 2; ++kk) {
            int kg = kk * 4 + lk;
            bf16x8 a[4], bb[6];
#pragma unroll
            for (int m = 0; m < 4; ++m) {
                int row = wm * 64 + m * 16 + lr;
                a[m] = *(const bf16x8*)&Pl[row * 64 + ((kg ^ (row & 7)) << 3)];
            }
#pragma unroll
            for (int n = 0; n < 6; ++n) {
                int col = wn * 96 + n * 16 + lr;
                bb[n] = *(const bf16x8*)&Rl[col * 64 + ((kg ^ (col & 7)) << 3)];
            }
            // swapped operands: A=R_frag (i rows), B=P_frag (o cols)
#pragma unroll
            for (int n = 0; n < 6; ++n)
#pragma unroll
                for (int m = 0; m < 4; ++m)
                    wacc[n][m] = __builtin_amdgcn_mfma_f32_16x16x32_bf16(
                        bb[n], a[m], wacc[n][m], 0, 0, 0);
        }
        __syncthreads();   // all Rl/Pl reads complete before overwrite

        // store W: D[i = wn*96+n*16+lk*4+j][o = wm*64+m*16+lr] -> b64 each
        // i>>3 = wn*12 + n*2 + (lk>>1)  (j-invariant);  i&7 = (lk&1)*4 + j
        uint16_t* Bs16 = (uint16_t*)arena;
#pragma unroll
        for (int n = 0; n < 6; ++n) {
            int ubase = (wn * 12 + n * 2 + (lk >> 1)) * 128;
#pragma unroll
            for (int m = 0; m < 4; ++m) {
                int o = wm * 64 + m * 16 + lr;
                u32x2 d;
                d[0] = pack2(wacc[n][m][0], wacc[n][m][1]);
                d[1] = pack2(wacc[n][m][2], wacc[n][m][3]);
                *(u32x2*)&Bs16[(size_t)(ubase + o) * 8 + (lk & 1) * 4] = d;
            }
        }
        __syncthreads();   // Bs ready
    }

    // ================= main: 12 flat steps, zero barriers ===================
    f32x4 accA[2][8], accB[2][8];
#pragma unroll
    for (int m = 0; m < 2; ++m)
#pragma unroll
        for (int n = 0; n < 8; ++n) {
            accA[m][n] = f32x4{0.f, 0.f, 0.f, 0.f};
            accB[m][n] = f32x4{0.f, 0.f, 0.f, 0.f};
        }

    const int a0s = ((2 * lk)     ^ (lr & 7)) << 4;
    const int a1s = ((2 * lk + 1) ^ (lr & 7)) << 4;

#pragma unroll
    for (int s = 0; s < 12; ++s) {
        if (s < 10) { WAIT_VM4(); } else { WAIT_VM0(); }
        __builtin_amdgcn_sched_barrier(0);

        const uint8_t* Abuf = Ab + (s & 1) * 4096;
        const int kk = s % 6;
        bf16x8 af[2], bfr[8];
#pragma unroll
        for (int m = 0; m < 2; ++m) {
            const uint8_t* p = Abuf + (m * 16 + lr) * 128;
            f32x4 lo = *(const f32x4*)(p + a0s);
            f32x4 hi = *(const f32x4*)(p + a1s);
            af[m] = cvt8(lo, hi);
        }
#pragma unroll
        for (int n = 0; n < 8; ++n)
            bfr[n] = *(const bf16x8*)(arena
                        + (((kk * 4 + lk) * 128 + n * 16 + lr) << 4));

        WAIT_LGKM0();                       // buf reads retired before reuse
        __builtin_amdgcn_sched_barrier(0);
        if (s < 10) stage(s + 2, s & 1);    // fire-and-forget, depth-2

        if (s < 6) {
#pragma unroll
            for (int m = 0; m < 2; ++m)
#pragma unroll
                for (int n = 0; n < 8; ++n)
                    accA[m][n] = __builtin_amdgcn_mfma_f32_16x16x32_bf16(
                        af[m], bfr[n], accA[m][n], 0, 0, 0);
        } else {
#pragma unroll
            for (int m = 0; m < 2; ++m)
#pragma unroll
                for (int n = 0; n < 8; ++n)
                    accB[m][n] = __builtin_amdgcn_mfma_f32_16x16x32_bf16(
                        af[m], bfr[n], accB[m][n], 0, 0, 0);
        }
    }

    // epilogue (R8-exact form), both halves
#pragma unroll
    for (int m = 0; m < 2; ++m) {
        int r0 = w * 32 + m * 16 + lk * 4;
#pragma unroll
        for (int n = 0; n < 8; ++n) {
            int c0 = n * 16 + lr;
#pragma unroll
            for (int j = 0; j < 4; ++j) {
                Yb[(size_t)(r0 + j) * OUTF + c0]       = accA[m][n][j];
                Yb[(size_t)(128 + r0 + j) * OUTF + c0] = accB[m][n][j];
            }
        }
    }
}

extern "C" void kernel_launch(void* const* d_in, const int* in_sizes, int n_in,
                              void* d_out, int out_size, void* d_ws, size_t ws_size,
                              hipStream_t stream) {
    (void)in_sizes; (void)n_in; (void)out_size; (void)d_ws; (void)ws_size;
    const float* state   = (const float*)d_in[0];
    const int*   session = (const int*)  d_in[1];
    const float* readin  = (const float*)d_in[2];
    const float* project = (const float*)d_in[3];
    float*       out     = (float*)d_out;

    hipLaunchKernelGGL(fused_gemm, dim3(1024), dim3(256), 0, stream,
                       state, session, readin, project, out);
}